// Round 5
// baseline (652.416 us; speedup 1.0000x reference)
//
#include <hip/hip_runtime.h>

typedef unsigned short u16;
typedef __attribute__((ext_vector_type(8))) short short8;
typedef __attribute__((ext_vector_type(4))) float f32x4;

__device__ __forceinline__ float bf2f(u16 u){ return __uint_as_float(((unsigned)u)<<16); }
__device__ __forceinline__ u16 f2bf(float f){
  unsigned u = __float_as_uint(f);
  unsigned r = u + 0x7fffu + ((u>>16)&1u);   // RNE (no NaN/inf in this problem)
  return (u16)(r>>16);
}

#define MFMA16(a,b,c) __builtin_amdgcn_mfma_f32_16x16x32_bf16(a,b,c,0,0,0)

// ---- attn LDS layout (u16 offsets). Goal: <=80KB -> 2 blocks/CU (16 waves).
// Xhi/Xlo 64x264 (67584 B). R: 5120-u16 multipurpose region, time-disjoint:
//   (a) per-wave private G tiles: 8 x 640 u16 (16 rows x 40, one plane at a
//       time, hi then lo) - no barriers, same-wave in-order DS ops;
//   (b) L-exchange slots: 4 rg x 512 f32 (= 4096 u16);
//   (c) Xv^T transpose slots: 2 x 2304 u16 (once, wave-pair rounds);
//   (d) Ps 64x72 = 4608 u16 + SMf 256 f32 (last 512 u16).
static constexpr int XS_STR  = 264;
static constexpr int PS_STR  = 72;
static constexpr int XLO_OFF = 16896;
static constexpr int R_OFF   = 33792;
static constexpr int SMF_U16 = 38400;                 // float[256]
static constexpr int SMEM_BYTES = 38912*2;            // 77824 B -> 2 blocks/CU

// ---- mh LDS: Qhi/Qlo 32x264 + Chi/Clo 64x40
static constexpr int MH_SMEM = 22016*2;               // 44032 B

// ---- ws layout (u16): mhi[524288] | mlo[524288] | khi[65536] | klo[65536]
//                       | vT[65536] | soP[4096 u16 = 2048 f32]   (~2.38 MB)

// prep: 0..63 ksplit | 64..79 vT | 80..335 so | 336..847 zero out
__global__ void prep_kernel(const float* __restrict__ k, const float* __restrict__ v,
                            const float* __restrict__ o, u16* __restrict__ khi,
                            u16* __restrict__ klo, u16* __restrict__ vT,
                            float* __restrict__ soP, float4* __restrict__ outz){
  __shared__ float Ts[64*65];
  const int blk = blockIdx.x, tid = threadIdx.x;
  if (blk < 64){
    int base = blk*1024 + tid*4;
    const float4 f4 = *(const float4*)(k + base);
    ushort4 hv, lv;
    hv.x=f2bf(f4.x); lv.x=f2bf(f4.x-bf2f(hv.x));
    hv.y=f2bf(f4.y); lv.y=f2bf(f4.y-bf2f(hv.y));
    hv.z=f2bf(f4.z); lv.z=f2bf(f4.z-bf2f(hv.z));
    hv.w=f2bf(f4.w); lv.w=f2bf(f4.w-bf2f(hv.w));
    *(ushort4*)&khi[base] = hv;
    *(ushort4*)&klo[base] = lv;
  } else if (blk < 80){
    int t = blk - 64;
    const int bi = (t>>2)<<6, bj = (t&3)<<6;
    #pragma unroll
    for (int p=0;p<4;p++){
      int idx4 = tid + (p<<8);
      int i = idx4 >> 4, c4 = (idx4 & 15) << 2;
      const float4 f4 = *(const float4*)(v + ((bi+i)<<8) + bj + c4);
      Ts[i*65+c4]=f4.x; Ts[i*65+c4+1]=f4.y; Ts[i*65+c4+2]=f4.z; Ts[i*65+c4+3]=f4.w;
    }
    __syncthreads();
    #pragma unroll
    for (int p=0;p<2;p++){
      int ch = tid + (p<<8);
      int j = ch >> 3, i8 = (ch & 7) << 3;
      short8 t8;
      #pragma unroll
      for (int e=0;e<8;e++) t8[e] = (short)f2bf(Ts[(i8+e)*65 + j]);
      *(short8*)&vT[((bj+j)<<8) + bi + i8] = t8;
    }
  } else if (blk < 336){
    int p = blk - 80;                      // 256 blocks: 8 h x 32 chunks of 8 rows
    int h = p >> 5, base = (p & 31) << 3;
    int w = tid >> 6, l = tid & 63;
    #pragma unroll
    for (int i=0;i<2;i++){
      int row = base + w*2 + i;
      const float4 f4 = *(const float4*)(o + (((h<<8)+row)<<8) + (l<<2));
      float s = f4.x + f4.y + f4.z + f4.w;
      #pragma unroll
      for (int off=32; off>=1; off>>=1) s += __shfl_xor(s, off, 64);
      if (l==0) soP[(h<<8)+row] = s;
    }
  } else {
    int z = blk - 336;                     // 512 blocks x 4096 float4
    const float4 zf4 = {0.f,0.f,0.f,0.f};
    #pragma unroll
    for (int i=0;i<16;i++) outz[z*4096 + i*256 + tid] = zf4;
  }
}

// MhT[h][dp][d] = sum_ko q[h][d][ko]*k[dp][ko], hi/lo bf16 via 3-term MFMA.
// 256 blocks (8h x 8 d-tiles(32) x 4 dp-tiles(64)).
__global__ __launch_bounds__(256,1) void mh_kernel(
    const float* __restrict__ q, const u16* __restrict__ khi,
    const u16* __restrict__ klo, u16* __restrict__ mhi, u16* __restrict__ mlo)
{
  extern __shared__ u16 sm[];
  u16* Qhi = sm;               // 32x264
  u16* Qlo = sm + 8448;
  u16* Chi = sm + 16896;       // 64x40  [dp-local][d-row-local]
  u16* Clo = sm + 19456;

  const int tid = threadIdx.x;
  const int w = tid >> 6, lane = tid & 63;
  const int quad = lane >> 4, m16 = lane & 15;
  const int cw2 = w << 4, koq = quad << 3;
  const int h   = blockIdx.x >> 5;
  const int rr  = blockIdx.x & 31;
  const int dt  = (rr >> 2) << 5;          // d-tile (32 rows)
  const int dpq = (rr & 3) << 6;           // dp-tile (64 cols)

  #pragma unroll
  for (int i=0;i<8;i++){
    int idx4 = i*256 + tid;
    int tr = idx4 >> 6, c4 = (idx4 & 63) << 2;
    const float4 xv = *(const float4*)(q + (((h<<8)+dt+tr)<<8) + c4);
    ushort4 hv, lv;
    hv.x=f2bf(xv.x); lv.x=f2bf(xv.x-bf2f(hv.x));
    hv.y=f2bf(xv.y); lv.y=f2bf(xv.y-bf2f(hv.y));
    hv.z=f2bf(xv.z); lv.z=f2bf(xv.z-bf2f(hv.z));
    hv.w=f2bf(xv.w); lv.w=f2bf(xv.w-bf2f(hv.w));
    *(ushort4*)&Qhi[tr*XS_STR + c4] = hv;
    *(ushort4*)&Qlo[tr*XS_STR + c4] = lv;
  }
  __syncthreads();

  const f32x4 zf = {0.f,0.f,0.f,0.f};
  f32x4 a0 = zf, a1 = zf;
  #pragma unroll
  for (int kk=0;kk<8;kk++){
    const int ko = (kk<<5) + koq;
    short8 Ah0 = *(const short8*)&Qhi[(m16)*XS_STR + ko];
    short8 Al0 = *(const short8*)&Qlo[(m16)*XS_STR + ko];
    short8 Ah1 = *(const short8*)&Qhi[(16+m16)*XS_STR + ko];
    short8 Al1 = *(const short8*)&Qlo[(16+m16)*XS_STR + ko];
    short8 Bh  = *(const short8*)&khi[(dpq+cw2+m16)*256 + ko];
    short8 Bl  = *(const short8*)&klo[(dpq+cw2+m16)*256 + ko];
    a0 = MFMA16(Ah0,Bh,a0); a0 = MFMA16(Ah0,Bl,a0); a0 = MFMA16(Al0,Bh,a0);
    a1 = MFMA16(Ah1,Bh,a1); a1 = MFMA16(Ah1,Bl,a1); a1 = MFMA16(Al1,Bh,a1);
  }

  const int dpl = cw2 + m16;
  #pragma unroll
  for (int g=0; g<4; g++){
    float v0 = a0[g]; u16 h0 = f2bf(v0);
    Chi[dpl*40 + quad*4+g] = h0;
    Clo[dpl*40 + quad*4+g] = f2bf(v0 - bf2f(h0));
    float v1 = a1[g]; u16 h1 = f2bf(v1);
    Chi[dpl*40 + 16 + quad*4+g] = h1;
    Clo[dpl*40 + 16 + quad*4+g] = f2bf(v1 - bf2f(h1));
  }
  __syncthreads();

  int dpo = tid >> 2, i8 = (tid & 3) << 3;
  *(int4*)&mhi[(((h<<8)+dpq+dpo)<<8) + dt + i8] = *(const int4*)&Chi[dpo*40 + i8];
  *(int4*)&mlo[(((h<<8)+dpq+dpo)<<8) + dt + i8] = *(const int4*)&Clo[dpo*40 + i8];
}

// Merged attention: blocks [0,512) branch 0 (per-(b,y), heads 0..3),
// [512,1024) branch 1 (per-(b,x), heads 4..7). out pre-zeroed; atomicAdd.
// 8 waves, wave role (rg = w&3: 16-row group; cp = w>>2: chunk parity AND
// z-half). Per head, 8 barrier-free chunks of 32 G-cols: wave computes its
// 16x32 G tile (mm3 3-term), bounces hi/lo planes through a PRIVATE 640-u16
// LDS tile (same-wave in-order DS read/write), accumulates its own logits
// partial (rows rg, all 64 z) - zero cross-wave deps. Wave pairs (rg,cp=0/1)
// then merge k-partials (2-round LDS exchange), softmax (z-half = cp), Ps,
// Y (XvB B-frags in regs).
// LAUNCH BOUNDS: empirically on this toolchain VGPR cap = 2048/(arg * B/64):
// (512,2)->128 ok (r0/r3); (512,4)->64 SPILL (r4); (1024,4)->64 SPILL (r1).
// So arg MUST be 2. Runtime occupancy comes from resources anyway:
// LDS 77824 B -> 2 blocks/CU and 128 VGPR -> 4 waves/SIMD -> 16 waves/CU.
// Tripwires: VGPR=128 (64 => cap model wrong), FETCH ~60MB, WRITE ~90MB
// (else spill); OccupancyPercent ~45 (else 2-block assumption failed).
__global__ __launch_bounds__(512,2) void attn_kernel(
    const float* __restrict__ x, const u16* __restrict__ mhiP,
    const u16* __restrict__ mloP, const u16* __restrict__ vT,
    const float* __restrict__ soP, float* __restrict__ out)
{
  extern __shared__ u16 sm[];
  u16* Xhi = sm;
  u16* Xlo = sm + XLO_OFF;
  u16* R   = sm + R_OFF;
  u16* Ps  = R;                          // 64x72 (aliases G-priv / L-exch)
  float* Rf  = (float*)R;                // L-exchange slots
  float* SMf = (float*)(sm + SMF_U16);   // [row][half][mx,sum]

  const int tid  = threadIdx.x;
  const int w    = tid >> 6, lane = tid & 63;
  const int quad = lane >> 4, m16 = lane & 15;
  const int br   = blockIdx.x >> 9;
  const int idx  = blockIdx.x & 511;
  const int b    = idx >> 6, s = idx & 63;
  const int cw   = w << 5;            // Xv/Y: 32-col strip
  const int rg   = w & 3;             // chunk loop + softmax: 16-row group
  const int cp   = w >> 2;            // chunk parity / z-half
  const int rs   = rg << 4;
  const int koq  = quad << 3;
  u16* Rw = R + w*640;                // private 16x40 G tile (one plane)

  auto tok = [&](int t)->int {
    int m = br ? s : t;
    int n = br ? t : s;
    return (((b<<6) + m) << 14) + (n << 8);
  };

  // ---- stage X hi/lo (4096 float4, 8 iters x 512 threads)
  #pragma unroll
  for (int i=0;i<8;i++){
    int idx4 = i*512 + tid;
    int tr = idx4 >> 6, c4 = (idx4 & 63) << 2;
    const float4 xv = *(const float4*)(x + tok(tr) + c4);
    ushort4 hv, lv;
    hv.x=f2bf(xv.x); lv.x=f2bf(xv.x-bf2f(hv.x));
    hv.y=f2bf(xv.y); lv.y=f2bf(xv.y-bf2f(hv.y));
    hv.z=f2bf(xv.z); lv.z=f2bf(xv.z-bf2f(hv.z));
    hv.w=f2bf(xv.w); lv.w=f2bf(xv.w-bf2f(hv.w));
    *(ushort4*)&Xhi[tr*XS_STR + c4] = hv;
    *(ushort4*)&Xlo[tr*XS_STR + c4] = lv;
  }
  __syncthreads();

  const f32x4 zf = {0.f,0.f,0.f,0.f};

  // ---- Xv = Xhi @ vT over wave's 32-col strip (acc in regs)
  f32x4 xacc[4][2];
  #pragma unroll
  for (int r=0;r<4;r++){ xacc[r][0] = zf; xacc[r][1] = zf; }
  #pragma unroll
  for (int kk=0;kk<8;kk++){
    const int ko = (kk<<5) + koq;
    short8 A[4], Bf[2];
    #pragma unroll
    for (int r=0;r<4;r++) A[r]  = *(const short8*)&Xhi[(r*16+m16)*XS_STR + ko];
    #pragma unroll
    for (int c=0;c<2;c++) Bf[c] = *(const short8*)&vT[(cw + c*16 + m16)*256 + ko];
    #pragma unroll
    for (int r=0;r<4;r++)
      #pragma unroll
      for (int c=0;c<2;c++) xacc[r][c] = MFMA16(A[r], Bf[c], xacc[r][c]);
  }
  // ---- transpose own strip to XvB regs via R, 2 waves per round (4 rounds)
  short8 XvB[2][2];
  for (int qq=0; qq<4; qq++){
    if ((w>>1) == qq){
      u16* slot = R + (w&1)*2304;        // [vc-local 32][72]
      #pragma unroll
      for (int r=0;r<4;r++)
        #pragma unroll
        for (int c=0;c<2;c++)
          #pragma unroll
          for (int g=0; g<4; g++)
            slot[(c*16+m16)*72 + (r*16 + quad*4 + g)] = f2bf(xacc[r][c][g]);
    }
    __syncthreads();
    if ((w>>1) == qq){
      u16* slot = R + (w&1)*2304;
      #pragma unroll
      for (int kk=0;kk<2;kk++)
        #pragma unroll
        for (int c=0;c<2;c++)
          XvB[kk][c] = *(const short8*)&slot[(c*16+m16)*72 + (kk<<5) + koq];
    }
    __syncthreads();
  }

  f32x4 Z[4][2];
  #pragma unroll
  for (int r=0;r<4;r++){ Z[r][0] = zf; Z[r][1] = zf; }

  for (int h=0; h<4; h++){
    const int gh = (br<<2) + h;
    const u16* __restrict__ Whi = mhiP + (gh<<16);
    const u16* __restrict__ Wlo = mloP + (gh<<16);

    f32x4 L0 = zf, L1 = zf, L2 = zf, L3 = zf;   // logits partial: rows rg, z 0..63

    // ---- 4 chunks (32 G-cols each, parity cp) - NO barriers inside
    #pragma unroll 1
    for (int i=0; i<4; i++){
      const int c = (i<<1) + cp;
      const int cb32 = c << 5;
      // mm3: G[rs..rs+16][cb32..cb32+32] = X @ Mh (3-term hi/lo)
      f32x4 a0 = zf, a1 = zf;
      #pragma unroll
      for (int kk=0;kk<8;kk++){
        const int ko = (kk<<5) + koq;
        short8 Ah = *(const short8*)&Xhi[(rs+m16)*XS_STR + ko];
        short8 Al = *(const short8*)&Xlo[(rs+m16)*XS_STR + ko];
        const u16* wp = Whi + (cb32+m16)*256 + ko;
        const u16* lp = Wlo + (cb32+m16)*256 + ko;
        short8 Bh0 = *(const short8*)wp;
        short8 Bl0 = *(const short8*)lp;
        short8 Bh1 = *(const short8*)(wp + 16*256);
        short8 Bl1 = *(const short8*)(lp + 16*256);
        a0 = MFMA16(Ah,Bh0,a0); a0 = MFMA16(Ah,Bl0,a0); a0 = MFMA16(Al,Bh0,a0);
        a1 = MFMA16(Ah,Bh1,a1); a1 = MFMA16(Ah,Bl1,a1); a1 = MFMA16(Al,Bh1,a1);
      }
      // hi plane -> private tile -> A-frag (same-wave in-order DS)
      #pragma unroll
      for (int g=0; g<4; g++){
        Rw[(quad*4+g)*40 + m16]      = f2bf(a0[g]);
        Rw[(quad*4+g)*40 + 16 + m16] = f2bf(a1[g]);
      }
      short8 Ghi8 = *(const short8*)&Rw[m16*40 + koq];
      const int dbase = cb32 + koq;
      short8 Bxh0 = *(const short8*)&Xhi[(m16)*XS_STR + dbase];
      short8 Bxh1 = *(const short8*)&Xhi[(16+m16)*XS_STR + dbase];
      short8 Bxh2 = *(const short8*)&Xhi[(32+m16)*XS_STR + dbase];
      short8 Bxh3 = *(const short8*)&Xhi[(48+m16)*XS_STR + dbase];
      { short8 t = *(const short8*)&Xlo[(m16)*XS_STR + dbase];
        L0 = MFMA16(Ghi8,Bxh0,L0); L0 = MFMA16(Ghi8,t,L0); }
      { short8 t = *(const short8*)&Xlo[(16+m16)*XS_STR + dbase];
        L1 = MFMA16(Ghi8,Bxh1,L1); L1 = MFMA16(Ghi8,t,L1); }
      { short8 t = *(const short8*)&Xlo[(32+m16)*XS_STR + dbase];
        L2 = MFMA16(Ghi8,Bxh2,L2); L2 = MFMA16(Ghi8,t,L2); }
      { short8 t = *(const short8*)&Xlo[(48+m16)*XS_STR + dbase];
        L3 = MFMA16(Ghi8,Bxh3,L3); L3 = MFMA16(Ghi8,t,L3); }
      // lo plane (overwrites hi; read of Ghi8 precedes in-order)
      #pragma unroll
      for (int g=0; g<4; g++){
        float v0 = a0[g]; u16 h0 = f2bf(v0);
        Rw[(quad*4+g)*40 + m16] = f2bf(v0 - bf2f(h0));
        float v1 = a1[g]; u16 h1 = f2bf(v1);
        Rw[(quad*4+g)*40 + 16 + m16] = f2bf(v1 - bf2f(h1));
      }
      short8 Glo8 = *(const short8*)&Rw[m16*40 + koq];
      L0 = MFMA16(Glo8,Bxh0,L0);
      L1 = MFMA16(Glo8,Bxh1,L1);
      L2 = MFMA16(Glo8,Bxh2,L2);
      L3 = MFMA16(Glo8,Bxh3,L3);
    }
    __syncthreads();                     // B1: private tiles dead, R free

    // ---- merge k-partials between wave pairs (rg, cp=0/1)
    if (cp == 0){
      #pragma unroll
      for (int g=0; g<4; g++){
        Rf[rg*512 +       (quad*4+g)*16 + m16] = L2[g];
        Rf[rg*512 + 256 + (quad*4+g)*16 + m16] = L3[g];
      }
    }
    __syncthreads();                     // B2
    if (cp == 1){
      #pragma unroll
      for (int g=0; g<4; g++){
        L2[g] += Rf[rg*512 +       (quad*4+g)*16 + m16];
        L3[g] += Rf[rg*512 + 256 + (quad*4+g)*16 + m16];
      }
      #pragma unroll
      for (int g=0; g<4; g++){
        Rf[rg*512 +       (quad*4+g)*16 + m16] = L0[g];
        Rf[rg*512 + 256 + (quad*4+g)*16 + m16] = L1[g];
      }
    }
    __syncthreads();                     // B3
    if (cp == 0){
      #pragma unroll
      for (int g=0; g<4; g++){
        L0[g] += Rf[rg*512 +       (quad*4+g)*16 + m16];
        L1[g] += Rf[rg*512 + 256 + (quad*4+g)*16 + m16];
      }
    }
    // wave now owns full-k logits for rows rs..rs+16, z-half cp

    // ---- softmax local (32-z half), cross-half merge via SMf
    float mxl[4], sml[4];
    auto smLocal = [&](f32x4& La, f32x4& Lb){
      #pragma unroll
      for (int g=0; g<4; g++){
        float mx = fmaxf(La[g], Lb[g]);
        #pragma unroll
        for (int off=1; off<16; off<<=1) mx = fmaxf(mx, __shfl_xor(mx, off, 64));
        float e0 = __expf(La[g]-mx), e1 = __expf(Lb[g]-mx);
        La[g] = e0; Lb[g] = e1;
        float sum = e0 + e1;
        #pragma unroll
        for (int off=1; off<16; off<<=1) sum += __shfl_xor(sum, off, 64);
        mxl[g] = mx; sml[g] = sum;
        if (m16 == 0){
          int row = rs + quad*4 + g;
          SMf[row*4 + cp*2]     = mx;
          SMf[row*4 + cp*2 + 1] = sum;
        }
      }
    };
    if (cp == 0) smLocal(L0, L1); else smLocal(L2, L3);
    __syncthreads();                     // B4: SMf visible (L-exch reads done)
    auto psW = [&](f32x4& La, f32x4& Lb){
      #pragma unroll
      for (int g=0; g<4; g++){
        int row = rs + quad*4 + g;
        float mxo = SMf[row*4 + (cp^1)*2];
        float smo = SMf[row*4 + (cp^1)*2 + 1];
        float M   = fmaxf(mxl[g], mxo);
        float al  = __expf(mxl[g]-M), ao = __expf(mxo-M);
        float scale = al / (sml[g]*al + smo*ao);
        Ps[row*PS_STR + (cp<<5) + m16]      = f2bf(La[g]*scale);
        Ps[row*PS_STR + (cp<<5) + 16 + m16] = f2bf(Lb[g]*scale);
      }
    };
    if (cp == 0) psW(L0, L1); else psW(L2, L3);
    __syncthreads();                     // B5: Ps visible

    // ---- Y = P @ Xv over wave's 32 cols (B from regs); Z += so * Y
    f32x4 ya[4][2];
    #pragma unroll
    for (int r=0;r<4;r++){ ya[r][0] = zf; ya[r][1] = zf; }
    #pragma unroll
    for (int kk=0;kk<2;kk++){
      const int ko = (kk<<5) + koq;
      short8 Ap[4];
      #pragma unroll
      for (int r=0;r<4;r++) Ap[r] = *(const short8*)&Ps[(r*16+m16)*PS_STR + ko];
      #pragma unroll
      for (int r=0;r<4;r++)
        #pragma unroll
        for (int c=0;c<2;c++) ya[r][c] = MFMA16(Ap[r], XvB[kk][c], ya[r][c]);
    }
    float sc0 = soP[gh*256 + cw + m16];
    float sc1 = soP[gh*256 + cw + 16 + m16];
    #pragma unroll
    for (int r=0;r<4;r++)
      #pragma unroll
      for (int g=0; g<4; g++){
        Z[r][0][g] += sc0*ya[r][0][g];
        Z[r][1][g] += sc1*ya[r][1][g];
      }
    __syncthreads();                     // B6: Ps reads done -> R reusable
  }

  // ---- epilogue: atomic accumulate into pre-zeroed out
  #pragma unroll
  for (int r=0;r<4;r++)
    #pragma unroll
    for (int c=0;c<2;c++)
      #pragma unroll
      for (int g=0; g<4; g++){
        int t   = r*16 + quad*4 + g;
        int col = cw + c*16 + m16;
        atomicAdd(&out[tok(t) + col], Z[r][c][g]);
      }
}

extern "C" void kernel_launch(void* const* d_in, const int* in_sizes, int n_in,
                              void* d_out, int out_size, void* d_ws, size_t ws_size,
                              hipStream_t stream) {
  const float* x = (const float*)d_in[0];
  const float* q = (const float*)d_in[1];
  const float* k = (const float*)d_in[2];
  const float* v = (const float*)d_in[3];
  const float* o = (const float*)d_in[4];
  u16* ws   = (u16*)d_ws;                    // ~2.38 MB
  u16* mhi  = ws;
  u16* mlo  = ws + 524288;
  u16* khi  = ws + 1048576;
  u16* klo  = ws + 1114112;
  u16* vT   = ws + 1179648;
  float* soP = (float*)(ws + 1245184);
  float* out = (float*)d_out;

  prep_kernel<<<848, 256, 0, stream>>>(k, v, o, khi, klo, vT, soP, (float4*)d_out);
  (void)hipFuncSetAttribute(reinterpret_cast<const void*>(&mh_kernel),
                            hipFuncAttributeMaxDynamicSharedMemorySize, MH_SMEM);
  mh_kernel<<<256, 256, MH_SMEM, stream>>>(q, khi, klo, mhi, mlo);

  (void)hipFuncSetAttribute(reinterpret_cast<const void*>(&attn_kernel),
                            hipFuncAttributeMaxDynamicSharedMemorySize, SMEM_BYTES);
  attn_kernel<<<1024, 512, SMEM_BYTES, stream>>>(x, mhi, mlo, vT, soP, out);
}

// Round 6
// 335.515 us; speedup vs baseline: 1.9445x; 1.9445x over previous
//
#include <hip/hip_runtime.h>

typedef unsigned short u16;
typedef __attribute__((ext_vector_type(8))) short short8;
typedef __attribute__((ext_vector_type(4))) float f32x4;

__device__ __forceinline__ float bf2f(u16 u){ return __uint_as_float(((unsigned)u)<<16); }
__device__ __forceinline__ u16 f2bf(float f){
  unsigned u = __float_as_uint(f);
  unsigned r = u + 0x7fffu + ((u>>16)&1u);   // RNE (no NaN/inf in this problem)
  return (u16)(r>>16);
}

#define MFMA16(a,b,c) __builtin_amdgcn_mfma_f32_16x16x32_bf16(a,b,c,0,0,0)

// ---- attn LDS layout (u16 offsets) - ROUND-0 VERBATIM (best known: attn
// 270us, VGPR 128 no-spill, MfmaUtil 22.7). Strides 264/72: row-stride ≡ 4
// banks -> fragment reads serialize only to the wave64 minimum.
static constexpr int XS_STR  = 264;
static constexpr int PS_STR  = 72;
static constexpr int WT_STR  = 72;
static constexpr int XHI_OFF = 0;         // 64x264
static constexpr int XLO_OFF = 16896;
static constexpr int GT_OFF  = 33792;     // 64x264, Ghi then Glo per head
static constexpr int XVT_OFF = 50688;     // 256x72, persistent Xv^T
static constexpr int PS_OFF  = 69120;     // 64x72
static constexpr int SMRE_OFF= 73728;     // 64 rows x 2 halves x (mx,sum) f32
static constexpr int SMEM_BYTES = (73728 + 512)*2;   // 148480 B

// ---- mh LDS: Qhi/Qlo 32x264 + Chi/Clo 64x40 (256-block version, r4/r5-proven)
static constexpr int MH_SMEM = 22016*2;   // 44032 B

// ---- ws layout (u16): mhi[524288] | mlo[524288] | khi[65536] | klo[65536]
//                       | vT[65536] | soP[4096 u16 = 2048 f32]   (~2.38 MB)

// prep: 0..63 ksplit | 64..79 vT | 80..335 so | 336..847 zero out
__global__ void prep_kernel(const float* __restrict__ k, const float* __restrict__ v,
                            const float* __restrict__ o, u16* __restrict__ khi,
                            u16* __restrict__ klo, u16* __restrict__ vT,
                            float* __restrict__ soP, float4* __restrict__ outz){
  __shared__ float Ts[64*65];
  const int blk = blockIdx.x, tid = threadIdx.x;
  if (blk < 64){
    int base = blk*1024 + tid*4;
    const float4 f4 = *(const float4*)(k + base);
    ushort4 hv, lv;
    hv.x=f2bf(f4.x); lv.x=f2bf(f4.x-bf2f(hv.x));
    hv.y=f2bf(f4.y); lv.y=f2bf(f4.y-bf2f(hv.y));
    hv.z=f2bf(f4.z); lv.z=f2bf(f4.z-bf2f(hv.z));
    hv.w=f2bf(f4.w); lv.w=f2bf(f4.w-bf2f(hv.w));
    *(ushort4*)&khi[base] = hv;
    *(ushort4*)&klo[base] = lv;
  } else if (blk < 80){
    int t = blk - 64;
    const int bi = (t>>2)<<6, bj = (t&3)<<6;
    #pragma unroll
    for (int p=0;p<4;p++){
      int idx4 = tid + (p<<8);
      int i = idx4 >> 4, c4 = (idx4 & 15) << 2;
      const float4 f4 = *(const float4*)(v + ((bi+i)<<8) + bj + c4);
      Ts[i*65+c4]=f4.x; Ts[i*65+c4+1]=f4.y; Ts[i*65+c4+2]=f4.z; Ts[i*65+c4+3]=f4.w;
    }
    __syncthreads();
    #pragma unroll
    for (int p=0;p<2;p++){
      int ch = tid + (p<<8);
      int j = ch >> 3, i8 = (ch & 7) << 3;
      short8 t8;
      #pragma unroll
      for (int e=0;e<8;e++) t8[e] = (short)f2bf(Ts[(i8+e)*65 + j]);
      *(short8*)&vT[((bj+j)<<8) + bi + i8] = t8;
    }
  } else if (blk < 336){
    int p = blk - 80;                      // 256 blocks: 8 h x 32 chunks of 8 rows
    int h = p >> 5, base = (p & 31) << 3;
    int w = tid >> 6, l = tid & 63;
    #pragma unroll
    for (int i=0;i<2;i++){
      int row = base + w*2 + i;
      const float4 f4 = *(const float4*)(o + (((h<<8)+row)<<8) + (l<<2));
      float s = f4.x + f4.y + f4.z + f4.w;
      #pragma unroll
      for (int off=32; off>=1; off>>=1) s += __shfl_xor(s, off, 64);
      if (l==0) soP[(h<<8)+row] = s;
    }
  } else {
    int z = blk - 336;                     // 512 blocks x 4096 float4
    const float4 zf4 = {0.f,0.f,0.f,0.f};
    #pragma unroll
    for (int i=0;i<16;i++) outz[z*4096 + i*256 + tid] = zf4;
  }
}

// MhT[h][dp][d] = sum_ko q[h][d][ko]*k[dp][ko], hi/lo bf16 via 3-term MFMA.
// 256 blocks (8h x 8 d-tiles(32) x 4 dp-tiles(64)) - full-GPU; r0's 32-block
// version used 12% of the chip and cost ~40-50us. This version passed r4/r5.
__global__ __launch_bounds__(256,1) void mh_kernel(
    const float* __restrict__ q, const u16* __restrict__ khi,
    const u16* __restrict__ klo, u16* __restrict__ mhi, u16* __restrict__ mlo)
{
  extern __shared__ u16 sm[];
  u16* Qhi = sm;               // 32x264
  u16* Qlo = sm + 8448;
  u16* Chi = sm + 16896;       // 64x40  [dp-local][d-row-local]
  u16* Clo = sm + 19456;

  const int tid = threadIdx.x;
  const int w = tid >> 6, lane = tid & 63;
  const int quad = lane >> 4, m16 = lane & 15;
  const int cw2 = w << 4, koq = quad << 3;
  const int h   = blockIdx.x >> 5;
  const int rr  = blockIdx.x & 31;
  const int dt  = (rr >> 2) << 5;          // d-tile (32 rows)
  const int dpq = (rr & 3) << 6;           // dp-tile (64 cols)

  #pragma unroll
  for (int i=0;i<8;i++){
    int idx4 = i*256 + tid;
    int tr = idx4 >> 6, c4 = (idx4 & 63) << 2;
    const float4 xv = *(const float4*)(q + (((h<<8)+dt+tr)<<8) + c4);
    ushort4 hv, lv;
    hv.x=f2bf(xv.x); lv.x=f2bf(xv.x-bf2f(hv.x));
    hv.y=f2bf(xv.y); lv.y=f2bf(xv.y-bf2f(hv.y));
    hv.z=f2bf(xv.z); lv.z=f2bf(xv.z-bf2f(hv.z));
    hv.w=f2bf(xv.w); lv.w=f2bf(xv.w-bf2f(hv.w));
    *(ushort4*)&Qhi[tr*XS_STR + c4] = hv;
    *(ushort4*)&Qlo[tr*XS_STR + c4] = lv;
  }
  __syncthreads();

  const f32x4 zf = {0.f,0.f,0.f,0.f};
  f32x4 a0 = zf, a1 = zf;
  #pragma unroll
  for (int kk=0;kk<8;kk++){
    const int ko = (kk<<5) + koq;
    short8 Ah0 = *(const short8*)&Qhi[(m16)*XS_STR + ko];
    short8 Al0 = *(const short8*)&Qlo[(m16)*XS_STR + ko];
    short8 Ah1 = *(const short8*)&Qhi[(16+m16)*XS_STR + ko];
    short8 Al1 = *(const short8*)&Qlo[(16+m16)*XS_STR + ko];
    short8 Bh  = *(const short8*)&khi[(dpq+cw2+m16)*256 + ko];
    short8 Bl  = *(const short8*)&klo[(dpq+cw2+m16)*256 + ko];
    a0 = MFMA16(Ah0,Bh,a0); a0 = MFMA16(Ah0,Bl,a0); a0 = MFMA16(Al0,Bh,a0);
    a1 = MFMA16(Ah1,Bh,a1); a1 = MFMA16(Ah1,Bl,a1); a1 = MFMA16(Al1,Bh,a1);
  }

  const int dpl = cw2 + m16;
  #pragma unroll
  for (int g=0; g<4; g++){
    float v0 = a0[g]; u16 h0 = f2bf(v0);
    Chi[dpl*40 + quad*4+g] = h0;
    Clo[dpl*40 + quad*4+g] = f2bf(v0 - bf2f(h0));
    float v1 = a1[g]; u16 h1 = f2bf(v1);
    Chi[dpl*40 + 16 + quad*4+g] = h1;
    Clo[dpl*40 + 16 + quad*4+g] = f2bf(v1 - bf2f(h1));
  }
  __syncthreads();

  int dpo = tid >> 2, i8 = (tid & 3) << 3;
  *(int4*)&mhi[(((h<<8)+dpq+dpo)<<8) + dt + i8] = *(const int4*)&Chi[dpo*40 + i8];
  *(int4*)&mlo[(((h<<8)+dpq+dpo)<<8) + dt + i8] = *(const int4*)&Clo[dpo*40 + i8];
}

// Merged attention - ROUND-0 VERBATIM (best known). blocks [0,512) branch 0
// (per-(b,y), heads 0..3), [512,1024) branch 1 (per-(b,x), heads 4..7).
// out pre-zeroed; atomicAdd. 8 waves: mm3/Xv/Y split 4rt x 2ct (1x global-B
// redundancy, dbuf prefetch); logits split 16-row x 32-z with B-side Xhi
// persisted in registers (XB). Do NOT touch: regalloc sits exactly at the
// 128-VGPR boundary (r1/r2/r3 each perturbed it and spilled/regressed).
__global__ __launch_bounds__(512,2) void attn_kernel(
    const float* __restrict__ x, const u16* __restrict__ mhiP,
    const u16* __restrict__ mloP, const u16* __restrict__ vT,
    const float* __restrict__ soP, float* __restrict__ out)
{
  extern __shared__ u16 sm[];
  u16* Xhi = sm + XHI_OFF;
  u16* Xlo = sm + XLO_OFF;
  u16* Gt  = sm + GT_OFF;
  u16* Xvt = sm + XVT_OFF;
  u16* Ps  = sm + PS_OFF;
  float* SMf = (float*)(sm + SMRE_OFF);   // [row][half][mx,sum]

  const int tid  = threadIdx.x;
  const int w    = tid >> 6, lane = tid & 63;
  const int quad = lane >> 4, m16 = lane & 15;
  const int br   = blockIdx.x >> 9;
  const int idx  = blockIdx.x & 511;
  const int b    = idx >> 6, s = idx & 63;
  const int cw   = w << 5;            // 32-col strip for mm3/Xv/Y
  const int rs   = (w >> 1) << 4;     // logits: 16-row strip
  const int zh   = w & 1;             // logits: z half (32 cols)
  const int koq  = quad << 3;

  auto tok = [&](int t)->int {
    int m = br ? s : t;
    int n = br ? t : s;
    return (((b<<6) + m) << 14) + (n << 8);
  };

  // ---- stage X hi/lo (4096 float4, 8 iters x 512 threads)
  #pragma unroll
  for (int i=0;i<8;i++){
    int idx4 = i*512 + tid;
    int tr = idx4 >> 6, c4 = (idx4 & 63) << 2;
    const float4 xv = *(const float4*)(x + tok(tr) + c4);
    ushort4 hv, lv;
    hv.x=f2bf(xv.x); lv.x=f2bf(xv.x-bf2f(hv.x));
    hv.y=f2bf(xv.y); lv.y=f2bf(xv.y-bf2f(hv.y));
    hv.z=f2bf(xv.z); lv.z=f2bf(xv.z-bf2f(hv.z));
    hv.w=f2bf(xv.w); lv.w=f2bf(xv.w-bf2f(hv.w));
    *(ushort4*)&Xhi[tr*XS_STR + c4] = hv;
    *(ushort4*)&Xlo[tr*XS_STR + c4] = lv;
  }
  __syncthreads();

  // ---- persist logits B-side Xhi fragments (constant across heads): 64 VGPRs
  short8 XB[16];
  #pragma unroll
  for (int kk=0;kk<8;kk++)
    #pragma unroll
    for (int c=0;c<2;c++)
      XB[kk*2+c] = *(const short8*)&Xhi[((zh<<5) + c*16 + m16)*XS_STR + (kk<<5) + koq];

  const f32x4 zf = {0.f,0.f,0.f,0.f};
  f32x4 acc[4][2];

  // acc = Xhi@Whi + Xhi@Wlo + Xlo@Whi over wave's 32-col strip, dbuf B-loads
  auto mm3 = [&](const u16* __restrict__ Whi, const u16* __restrict__ Wlo){
    #pragma unroll
    for (int r=0;r<4;r++){ acc[r][0] = zf; acc[r][1] = zf; }
    short8 Bh[2][2], Bl[2][2];
    #pragma unroll
    for (int c=0;c<2;c++){
      Bh[0][c] = *(const short8*)&Whi[(cw + c*16 + m16)*256 + koq];
      Bl[0][c] = *(const short8*)&Wlo[(cw + c*16 + m16)*256 + koq];
    }
    #pragma unroll
    for (int kk=0;kk<8;kk++){
      const int cur = kk&1, nxt = cur^1;
      if (kk<7){
        const int ko2 = ((kk+1)<<5) + koq;
        #pragma unroll
        for (int c=0;c<2;c++){
          Bh[nxt][c] = *(const short8*)&Whi[(cw + c*16 + m16)*256 + ko2];
          Bl[nxt][c] = *(const short8*)&Wlo[(cw + c*16 + m16)*256 + ko2];
        }
      }
      const int ko = (kk<<5) + koq;
      short8 Ah[4], Al[4];
      #pragma unroll
      for (int r=0;r<4;r++) Ah[r] = *(const short8*)&Xhi[(r*16+m16)*XS_STR + ko];
      #pragma unroll
      for (int r=0;r<4;r++) Al[r] = *(const short8*)&Xlo[(r*16+m16)*XS_STR + ko];
      #pragma unroll
      for (int r=0;r<4;r++)
        #pragma unroll
        for (int c=0;c<2;c++){
          acc[r][c] = MFMA16(Ah[r], Bh[cur][c], acc[r][c]);
          acc[r][c] = MFMA16(Ah[r], Bl[cur][c], acc[r][c]);
          acc[r][c] = MFMA16(Al[r], Bh[cur][c], acc[r][c]);
        }
    }
  };

  // ---- Xv = Xhi @ vT over wave's 32 cols; store Xv^T (unscaled) in LDS
  {
    #pragma unroll
    for (int r=0;r<4;r++){ acc[r][0] = zf; acc[r][1] = zf; }
    #pragma unroll
    for (int kk=0;kk<8;kk++){
      const int ko = (kk<<5) + koq;
      short8 A[4], Bf[2];
      #pragma unroll
      for (int r=0;r<4;r++) A[r]  = *(const short8*)&Xhi[(r*16+m16)*XS_STR + ko];
      #pragma unroll
      for (int c=0;c<2;c++) Bf[c] = *(const short8*)&vT[(cw + c*16 + m16)*256 + ko];
      #pragma unroll
      for (int r=0;r<4;r++)
        #pragma unroll
        for (int c=0;c<2;c++) acc[r][c] = MFMA16(A[r], Bf[c], acc[r][c]);
    }
    #pragma unroll
    for (int r=0;r<4;r++)
      #pragma unroll
      for (int c=0;c<2;c++)
        #pragma unroll
        for (int g=0; g<4; g++){
          int z  = r*16 + quad*4 + g;
          int vc = cw + c*16 + m16;
          Xvt[vc*WT_STR + z] = f2bf(acc[r][c][g]);
        }
    // visible after bar1 of head 0
  }

  f32x4 Z[4][2];
  #pragma unroll
  for (int r=0;r<4;r++){ Z[r][0] = zf; Z[r][1] = zf; }

  for (int h=0; h<4; h++){
    const int gh = br*4 + h;

    // ---- G = X @ Mh[gh] (3-term hi/lo); write Ghi (all rows x own 32 cols)
    mm3(mhiP + gh*65536, mloP + gh*65536);
    #pragma unroll
    for (int r=0;r<4;r++)
      #pragma unroll
      for (int c=0;c<2;c++)
        #pragma unroll
        for (int g=0; g<4; g++){
          int row = r*16 + quad*4 + g;
          int col = cw + c*16 + m16;
          Gt[row*XS_STR + col] = f2bf(acc[r][c][g]);
        }
    __syncthreads();                       // bar1: Ghi (+Xvt at h==0) visible

    // ---- logits A: Ghi@Xhi^T (regs) + Ghi@Xlo^T. Rows rs..rs+16, z half zh.
    f32x4 L[2];
    L[0] = zf; L[1] = zf;
    #pragma unroll
    for (int kk=0;kk<8;kk++){
      const int ko = (kk<<5) + koq;
      short8 A = *(const short8*)&Gt[(rs+m16)*XS_STR + ko];
      #pragma unroll
      for (int c=0;c<2;c++){
        L[c] = MFMA16(A, XB[kk*2+c], L[c]);
        short8 Bl = *(const short8*)&Xlo[((zh<<5) + c*16 + m16)*XS_STR + ko];
        L[c] = MFMA16(A, Bl, L[c]);
      }
    }
    __syncthreads();                       // bar2: Gt-hi reads done -> overwrite
    #pragma unroll
    for (int r=0;r<4;r++)
      #pragma unroll
      for (int c=0;c<2;c++)
        #pragma unroll
        for (int g=0; g<4; g++){
          int row = r*16 + quad*4 + g;
          int col = cw + c*16 + m16;
          float vv = acc[r][c][g];
          u16 hh = f2bf(vv);
          Gt[row*XS_STR + col] = f2bf(vv - bf2f(hh));   // Glo
        }
    __syncthreads();                       // bar3: Glo visible

    // ---- logits B: Glo@Xhi^T (regs)
    #pragma unroll
    for (int kk=0;kk<8;kk++){
      const int ko = (kk<<5) + koq;
      short8 A = *(const short8*)&Gt[(rs+m16)*XS_STR + ko];
      #pragma unroll
      for (int c=0;c<2;c++)
        L[c] = MFMA16(A, XB[kk*2+c], L[c]);
    }

    // ---- softmax: local (32-z half) max/sum, cross-wave merge via SMf
    float mxl[4], sml[4];
    #pragma unroll
    for (int g=0; g<4; g++){
      float mx = fmaxf(L[0][g], L[1][g]);
      #pragma unroll
      for (int off=1; off<16; off<<=1) mx = fmaxf(mx, __shfl_xor(mx, off, 64));
      float sum = 0.f;
      #pragma unroll
      for (int c=0;c<2;c++){ float e = __expf(L[c][g]-mx); L[c][g] = e; sum += e; }
      #pragma unroll
      for (int off=1; off<16; off<<=1) sum += __shfl_xor(sum, off, 64);
      mxl[g] = mx; sml[g] = sum;
      if (m16 == 0){
        int row = rs + quad*4 + g;
        SMf[row*4 + zh*2]     = mx;
        SMf[row*4 + zh*2 + 1] = sum;
      }
    }
    __syncthreads();                       // bar4: SMf visible
    #pragma unroll
    for (int g=0; g<4; g++){
      int row = rs + quad*4 + g;
      float mxo = SMf[row*4 + (zh^1)*2];
      float smo = SMf[row*4 + (zh^1)*2 + 1];
      float M   = fmaxf(mxl[g], mxo);
      float al  = __expf(mxl[g]-M), ao = __expf(mxo-M);
      float scale = al / (sml[g]*al + smo*ao);
      #pragma unroll
      for (int c=0;c<2;c++)
        Ps[row*PS_STR + (zh<<5) + c*16 + m16] = f2bf(L[c][g]*scale);
    }
    __syncthreads();                       // bar5: Ps visible

    // ---- Y = P @ Xv over wave's 32 cols; Z += so * Y
    #pragma unroll
    for (int r=0;r<4;r++){ acc[r][0] = zf; acc[r][1] = zf; }
    #pragma unroll
    for (int kk=0;kk<2;kk++){
      const int ko = (kk<<5) + koq;
      short8 A[4], Bf[2];
      #pragma unroll
      for (int r=0;r<4;r++) A[r]  = *(const short8*)&Ps[(r*16+m16)*PS_STR + ko];
      #pragma unroll
      for (int c=0;c<2;c++) Bf[c] = *(const short8*)&Xvt[(cw + c*16 + m16)*WT_STR + ko];
      #pragma unroll
      for (int r=0;r<4;r++)
        #pragma unroll
        for (int c=0;c<2;c++) acc[r][c] = MFMA16(A[r], Bf[c], acc[r][c]);
    }
    float sc[2];
    sc[0] = soP[gh*256 + cw + m16];
    sc[1] = soP[gh*256 + cw + 16 + m16];
    #pragma unroll
    for (int r=0;r<4;r++)
      #pragma unroll
      for (int c=0;c<2;c++)
        #pragma unroll
        for (int g=0; g<4; g++) Z[r][c][g] += sc[c]*acc[r][c][g];
    // no trailing barrier: next head's Gt writes precede bar1; all Gt/Ps/SMf
    // reads of head h complete before that head's bar4/bar5.
  }

  // ---- epilogue: atomic accumulate into pre-zeroed out
  #pragma unroll
  for (int r=0;r<4;r++)
    #pragma unroll
    for (int c=0;c<2;c++)
      #pragma unroll
      for (int g=0; g<4; g++){
        int t   = r*16 + quad*4 + g;
        int col = cw + c*16 + m16;
        atomicAdd(&out[tok(t) + col], Z[r][c][g]);
      }
}

extern "C" void kernel_launch(void* const* d_in, const int* in_sizes, int n_in,
                              void* d_out, int out_size, void* d_ws, size_t ws_size,
                              hipStream_t stream) {
  const float* x = (const float*)d_in[0];
  const float* q = (const float*)d_in[1];
  const float* k = (const float*)d_in[2];
  const float* v = (const float*)d_in[3];
  const float* o = (const float*)d_in[4];
  u16* ws   = (u16*)d_ws;                    // ~2.38 MB
  u16* mhi  = ws;
  u16* mlo  = ws + 524288;
  u16* khi  = ws + 1048576;
  u16* klo  = ws + 1114112;
  u16* vT   = ws + 1179648;
  float* soP = (float*)(ws + 1245184);
  float* out = (float*)d_out;

  prep_kernel<<<848, 256, 0, stream>>>(k, v, o, khi, klo, vT, soP, (float4*)d_out);
  (void)hipFuncSetAttribute(reinterpret_cast<const void*>(&mh_kernel),
                            hipFuncAttributeMaxDynamicSharedMemorySize, MH_SMEM);
  mh_kernel<<<256, 256, MH_SMEM, stream>>>(q, khi, klo, mhi, mlo);

  (void)hipFuncSetAttribute(reinterpret_cast<const void*>(&attn_kernel),
                            hipFuncAttributeMaxDynamicSharedMemorySize, SMEM_BYTES);
  attn_kernel<<<1024, 512, SMEM_BYTES, stream>>>(x, mhi, mlo, vT, soP, out);
}

// Round 7
// 331.917 us; speedup vs baseline: 1.9656x; 1.0108x over previous
//
#include <hip/hip_runtime.h>

typedef unsigned short u16;
typedef __attribute__((ext_vector_type(8))) short short8;
typedef __attribute__((ext_vector_type(4))) float f32x4;

__device__ __forceinline__ float bf2f(u16 u){ return __uint_as_float(((unsigned)u)<<16); }
__device__ __forceinline__ u16 f2bf(float f){
  unsigned u = __float_as_uint(f);
  unsigned r = u + 0x7fffu + ((u>>16)&1u);   // RNE (no NaN/inf in this problem)
  return (u16)(r>>16);
}

#define MFMA16(a,b,c) __builtin_amdgcn_mfma_f32_16x16x32_bf16(a,b,c,0,0,0)

// ---- attn LDS layout (u16 offsets) - ROUND-0 VERBATIM (best known: attn
// ~268us, VGPR 128 no-spill, MfmaUtil 22.9). Strides 264/72: row-stride ≡ 4
// banks -> fragment reads serialize only to the wave64 minimum.
static constexpr int XS_STR  = 264;
static constexpr int PS_STR  = 72;
static constexpr int WT_STR  = 72;
static constexpr int XHI_OFF = 0;         // 64x264
static constexpr int XLO_OFF = 16896;
static constexpr int GT_OFF  = 33792;     // 64x264, Ghi then Glo per head
static constexpr int XVT_OFF = 50688;     // 256x72, persistent Xv^T
static constexpr int PS_OFF  = 69120;     // 64x72
static constexpr int SMRE_OFF= 73728;     // 64 rows x 2 halves x (mx,sum) f32
static constexpr int SMEM_BYTES = (73728 + 512)*2;   // 148480 B

// ---- prep_mh LDS: mh role Qhi/Qlo 32x264 + Chi/Clo 64x40 (vT role reuses
// the same buffer as float Ts[64*65] = 16640 B < 44032 B)
static constexpr int MH_SMEM = 22016*2;   // 44032 B

// ---- ws layout (u16): mhi[524288] | mlo[524288] | (unused 131072)
//                       | vT[65536] | soP[4096 u16 = 2048 f32]   (~2.38 MB)

// Fused prep+mh: ONE dispatch (was prep+mh serialized; the ~67us non-attn
// time in r6 was dominated by launch gaps + un-overlapped zeroing, not
// compute). Roles: blk<256 mh (k converted inline from f32 - L2-resident,
// no khi/klo dependency) | 256..271 vT | 272..527 so | 528..1039 zero out.
__global__ __launch_bounds__(256,1) void prep_mh_kernel(
    const float* __restrict__ q, const float* __restrict__ k,
    const float* __restrict__ v, const float* __restrict__ o,
    u16* __restrict__ mhi, u16* __restrict__ mlo, u16* __restrict__ vT,
    float* __restrict__ soP, float4* __restrict__ outz)
{
  extern __shared__ u16 sm[];
  const int blk = blockIdx.x, tid = threadIdx.x;

  if (blk < 256){
    // ---- mh role: MhT[h][dp][d] = sum_ko q[h][d][ko]*k[dp][ko], hi/lo bf16
    // 256 blocks (8h x 8 d-tiles(32) x 4 dp-tiles(64))
    u16* Qhi = sm;               // 32x264
    u16* Qlo = sm + 8448;
    u16* Chi = sm + 16896;       // 64x40  [dp-local][d-row-local]
    u16* Clo = sm + 19456;

    const int w = tid >> 6, lane = tid & 63;
    const int quad = lane >> 4, m16 = lane & 15;
    const int cw2 = w << 4, koq = quad << 3;
    const int h   = blk >> 5;
    const int rr  = blk & 31;
    const int dt  = (rr >> 2) << 5;          // d-tile (32 rows)
    const int dpq = (rr & 3) << 6;           // dp-tile (64 cols)

    #pragma unroll
    for (int i=0;i<8;i++){
      int idx4 = i*256 + tid;
      int tr = idx4 >> 6, c4 = (idx4 & 63) << 2;
      const float4 xv = *(const float4*)(q + (((h<<8)+dt+tr)<<8) + c4);
      ushort4 hv, lv;
      hv.x=f2bf(xv.x); lv.x=f2bf(xv.x-bf2f(hv.x));
      hv.y=f2bf(xv.y); lv.y=f2bf(xv.y-bf2f(hv.y));
      hv.z=f2bf(xv.z); lv.z=f2bf(xv.z-bf2f(hv.z));
      hv.w=f2bf(xv.w); lv.w=f2bf(xv.w-bf2f(hv.w));
      *(ushort4*)&Qhi[tr*XS_STR + c4] = hv;
      *(ushort4*)&Qlo[tr*XS_STR + c4] = lv;
    }
    __syncthreads();

    const float* kptr = k + (dpq+cw2+m16)*256;   // this lane's k row
    const f32x4 zf = {0.f,0.f,0.f,0.f};
    f32x4 a0 = zf, a1 = zf;
    #pragma unroll
    for (int kk=0;kk<8;kk++){
      const int ko = (kk<<5) + koq;
      short8 Ah0 = *(const short8*)&Qhi[(m16)*XS_STR + ko];
      short8 Al0 = *(const short8*)&Qlo[(m16)*XS_STR + ko];
      short8 Ah1 = *(const short8*)&Qhi[(16+m16)*XS_STR + ko];
      short8 Al1 = *(const short8*)&Qlo[(16+m16)*XS_STR + ko];
      // inline k -> bf16 hi/lo (replaces khi/klo workspace round-trip)
      short8 Bh, Bl;
      {
        const float4 f0 = *(const float4*)(kptr + ko);
        const float4 f1 = *(const float4*)(kptr + ko + 4);
        float fv[8] = {f0.x,f0.y,f0.z,f0.w,f1.x,f1.y,f1.z,f1.w};
        #pragma unroll
        for (int e=0;e<8;e++){
          u16 hh = f2bf(fv[e]);
          Bh[e] = (short)hh;
          Bl[e] = (short)f2bf(fv[e]-bf2f(hh));
        }
      }
      a0 = MFMA16(Ah0,Bh,a0); a0 = MFMA16(Ah0,Bl,a0); a0 = MFMA16(Al0,Bh,a0);
      a1 = MFMA16(Ah1,Bh,a1); a1 = MFMA16(Ah1,Bl,a1); a1 = MFMA16(Al1,Bh,a1);
    }

    const int dpl = cw2 + m16;
    #pragma unroll
    for (int g=0; g<4; g++){
      float v0 = a0[g]; u16 h0 = f2bf(v0);
      Chi[dpl*40 + quad*4+g] = h0;
      Clo[dpl*40 + quad*4+g] = f2bf(v0 - bf2f(h0));
      float v1 = a1[g]; u16 h1 = f2bf(v1);
      Chi[dpl*40 + 16 + quad*4+g] = h1;
      Clo[dpl*40 + 16 + quad*4+g] = f2bf(v1 - bf2f(h1));
    }
    __syncthreads();

    int dpo = tid >> 2, i8 = (tid & 3) << 3;
    *(int4*)&mhi[(((h<<8)+dpq+dpo)<<8) + dt + i8] = *(const int4*)&Chi[dpo*40 + i8];
    *(int4*)&mlo[(((h<<8)+dpq+dpo)<<8) + dt + i8] = *(const int4*)&Clo[dpo*40 + i8];

  } else if (blk < 272){
    // ---- vT role (16 blocks)
    float* Ts = (float*)sm;                // 64x65
    int t = blk - 256;
    const int bi = (t>>2)<<6, bj = (t&3)<<6;
    #pragma unroll
    for (int p=0;p<4;p++){
      int idx4 = tid + (p<<8);
      int i = idx4 >> 4, c4 = (idx4 & 15) << 2;
      const float4 f4 = *(const float4*)(v + ((bi+i)<<8) + bj + c4);
      Ts[i*65+c4]=f4.x; Ts[i*65+c4+1]=f4.y; Ts[i*65+c4+2]=f4.z; Ts[i*65+c4+3]=f4.w;
    }
    __syncthreads();
    #pragma unroll
    for (int p=0;p<2;p++){
      int ch = tid + (p<<8);
      int j = ch >> 3, i8 = (ch & 7) << 3;
      short8 t8;
      #pragma unroll
      for (int e=0;e<8;e++) t8[e] = (short)f2bf(Ts[(i8+e)*65 + j]);
      *(short8*)&vT[((bj+j)<<8) + bi + i8] = t8;
    }
  } else if (blk < 528){
    // ---- so role (256 blocks: 8 h x 32 chunks of 8 rows)
    int p = blk - 272;
    int h = p >> 5, base = (p & 31) << 3;
    int w = tid >> 6, l = tid & 63;
    #pragma unroll
    for (int i=0;i<2;i++){
      int row = base + w*2 + i;
      const float4 f4 = *(const float4*)(o + (((h<<8)+row)<<8) + (l<<2));
      float s = f4.x + f4.y + f4.z + f4.w;
      #pragma unroll
      for (int off=32; off>=1; off>>=1) s += __shfl_xor(s, off, 64);
      if (l==0) soP[(h<<8)+row] = s;
    }
  } else {
    // ---- zero-out role (512 blocks x 4096 float4)
    int z = blk - 528;
    const float4 zf4 = {0.f,0.f,0.f,0.f};
    #pragma unroll
    for (int i=0;i<16;i++) outz[z*4096 + i*256 + tid] = zf4;
  }
}

// Merged attention - ROUND-0 core (do NOT touch structure: regalloc sits
// exactly at the 128-VGPR boundary; r1/r2/r3 each perturbed it and spilled).
// ONLY change vs r6: s_setprio(1)/(0) wrapping the MFMA clusters in mm3 and
// logits (T5: +4-7% on attn-shaped kernels, zero register cost).
// blocks [0,512) branch 0 (per-(b,y), heads 0..3), [512,1024) branch 1
// (per-(b,x), heads 4..7). out pre-zeroed; atomicAdd.
__global__ __launch_bounds__(512,2) void attn_kernel(
    const float* __restrict__ x, const u16* __restrict__ mhiP,
    const u16* __restrict__ mloP, const u16* __restrict__ vT,
    const float* __restrict__ soP, float* __restrict__ out)
{
  extern __shared__ u16 sm[];
  u16* Xhi = sm + XHI_OFF;
  u16* Xlo = sm + XLO_OFF;
  u16* Gt  = sm + GT_OFF;
  u16* Xvt = sm + XVT_OFF;
  u16* Ps  = sm + PS_OFF;
  float* SMf = (float*)(sm + SMRE_OFF);   // [row][half][mx,sum]

  const int tid  = threadIdx.x;
  const int w    = tid >> 6, lane = tid & 63;
  const int quad = lane >> 4, m16 = lane & 15;
  const int br   = blockIdx.x >> 9;
  const int idx  = blockIdx.x & 511;
  const int b    = idx >> 6, s = idx & 63;
  const int cw   = w << 5;            // 32-col strip for mm3/Xv/Y
  const int rs   = (w >> 1) << 4;     // logits: 16-row strip
  const int zh   = w & 1;             // logits: z half (32 cols)
  const int koq  = quad << 3;

  auto tok = [&](int t)->int {
    int m = br ? s : t;
    int n = br ? t : s;
    return (((b<<6) + m) << 14) + (n << 8);
  };

  // ---- stage X hi/lo (4096 float4, 8 iters x 512 threads)
  #pragma unroll
  for (int i=0;i<8;i++){
    int idx4 = i*512 + tid;
    int tr = idx4 >> 6, c4 = (idx4 & 63) << 2;
    const float4 xv = *(const float4*)(x + tok(tr) + c4);
    ushort4 hv, lv;
    hv.x=f2bf(xv.x); lv.x=f2bf(xv.x-bf2f(hv.x));
    hv.y=f2bf(xv.y); lv.y=f2bf(xv.y-bf2f(hv.y));
    hv.z=f2bf(xv.z); lv.z=f2bf(xv.z-bf2f(hv.z));
    hv.w=f2bf(xv.w); lv.w=f2bf(xv.w-bf2f(hv.w));
    *(ushort4*)&Xhi[tr*XS_STR + c4] = hv;
    *(ushort4*)&Xlo[tr*XS_STR + c4] = lv;
  }
  __syncthreads();

  // ---- persist logits B-side Xhi fragments (constant across heads): 64 VGPRs
  short8 XB[16];
  #pragma unroll
  for (int kk=0;kk<8;kk++)
    #pragma unroll
    for (int c=0;c<2;c++)
      XB[kk*2+c] = *(const short8*)&Xhi[((zh<<5) + c*16 + m16)*XS_STR + (kk<<5) + koq];

  const f32x4 zf = {0.f,0.f,0.f,0.f};
  f32x4 acc[4][2];

  // acc = Xhi@Whi + Xhi@Wlo + Xlo@Whi over wave's 32-col strip, dbuf B-loads
  auto mm3 = [&](const u16* __restrict__ Whi, const u16* __restrict__ Wlo){
    #pragma unroll
    for (int r=0;r<4;r++){ acc[r][0] = zf; acc[r][1] = zf; }
    short8 Bh[2][2], Bl[2][2];
    #pragma unroll
    for (int c=0;c<2;c++){
      Bh[0][c] = *(const short8*)&Whi[(cw + c*16 + m16)*256 + koq];
      Bl[0][c] = *(const short8*)&Wlo[(cw + c*16 + m16)*256 + koq];
    }
    #pragma unroll
    for (int kk=0;kk<8;kk++){
      const int cur = kk&1, nxt = cur^1;
      if (kk<7){
        const int ko2 = ((kk+1)<<5) + koq;
        #pragma unroll
        for (int c=0;c<2;c++){
          Bh[nxt][c] = *(const short8*)&Whi[(cw + c*16 + m16)*256 + ko2];
          Bl[nxt][c] = *(const short8*)&Wlo[(cw + c*16 + m16)*256 + ko2];
        }
      }
      const int ko = (kk<<5) + koq;
      short8 Ah[4], Al[4];
      #pragma unroll
      for (int r=0;r<4;r++) Ah[r] = *(const short8*)&Xhi[(r*16+m16)*XS_STR + ko];
      #pragma unroll
      for (int r=0;r<4;r++) Al[r] = *(const short8*)&Xlo[(r*16+m16)*XS_STR + ko];
      __builtin_amdgcn_s_setprio(1);
      #pragma unroll
      for (int r=0;r<4;r++)
        #pragma unroll
        for (int c=0;c<2;c++){
          acc[r][c] = MFMA16(Ah[r], Bh[cur][c], acc[r][c]);
          acc[r][c] = MFMA16(Ah[r], Bl[cur][c], acc[r][c]);
          acc[r][c] = MFMA16(Al[r], Bh[cur][c], acc[r][c]);
        }
      __builtin_amdgcn_s_setprio(0);
    }
  };

  // ---- Xv = Xhi @ vT over wave's 32 cols; store Xv^T (unscaled) in LDS
  {
    #pragma unroll
    for (int r=0;r<4;r++){ acc[r][0] = zf; acc[r][1] = zf; }
    #pragma unroll
    for (int kk=0;kk<8;kk++){
      const int ko = (kk<<5) + koq;
      short8 A[4], Bf[2];
      #pragma unroll
      for (int r=0;r<4;r++) A[r]  = *(const short8*)&Xhi[(r*16+m16)*XS_STR + ko];
      #pragma unroll
      for (int c=0;c<2;c++) Bf[c] = *(const short8*)&vT[(cw + c*16 + m16)*256 + ko];
      #pragma unroll
      for (int r=0;r<4;r++)
        #pragma unroll
        for (int c=0;c<2;c++) acc[r][c] = MFMA16(A[r], Bf[c], acc[r][c]);
    }
    #pragma unroll
    for (int r=0;r<4;r++)
      #pragma unroll
      for (int c=0;c<2;c++)
        #pragma unroll
        for (int g=0; g<4; g++){
          int z  = r*16 + quad*4 + g;
          int vc = cw + c*16 + m16;
          Xvt[vc*WT_STR + z] = f2bf(acc[r][c][g]);
        }
    // visible after bar1 of head 0
  }

  f32x4 Z[4][2];
  #pragma unroll
  for (int r=0;r<4;r++){ Z[r][0] = zf; Z[r][1] = zf; }

  for (int h=0; h<4; h++){
    const int gh = br*4 + h;

    // ---- G = X @ Mh[gh] (3-term hi/lo); write Ghi (all rows x own 32 cols)
    mm3(mhiP + gh*65536, mloP + gh*65536);
    #pragma unroll
    for (int r=0;r<4;r++)
      #pragma unroll
      for (int c=0;c<2;c++)
        #pragma unroll
        for (int g=0; g<4; g++){
          int row = r*16 + quad*4 + g;
          int col = cw + c*16 + m16;
          Gt[row*XS_STR + col] = f2bf(acc[r][c][g]);
        }
    __syncthreads();                       // bar1: Ghi (+Xvt at h==0) visible

    // ---- logits A: Ghi@Xhi^T (regs) + Ghi@Xlo^T. Rows rs..rs+16, z half zh.
    f32x4 L[2];
    L[0] = zf; L[1] = zf;
    #pragma unroll
    for (int kk=0;kk<8;kk++){
      const int ko = (kk<<5) + koq;
      short8 A = *(const short8*)&Gt[(rs+m16)*XS_STR + ko];
      short8 Bl0 = *(const short8*)&Xlo[((zh<<5) + m16)*XS_STR + ko];
      short8 Bl1 = *(const short8*)&Xlo[((zh<<5) + 16 + m16)*XS_STR + ko];
      __builtin_amdgcn_s_setprio(1);
      L[0] = MFMA16(A, XB[kk*2+0], L[0]);
      L[0] = MFMA16(A, Bl0, L[0]);
      L[1] = MFMA16(A, XB[kk*2+1], L[1]);
      L[1] = MFMA16(A, Bl1, L[1]);
      __builtin_amdgcn_s_setprio(0);
    }
    __syncthreads();                       // bar2: Gt-hi reads done -> overwrite
    #pragma unroll
    for (int r=0;r<4;r++)
      #pragma unroll
      for (int c=0;c<2;c++)
        #pragma unroll
        for (int g=0; g<4; g++){
          int row = r*16 + quad*4 + g;
          int col = cw + c*16 + m16;
          float vv = acc[r][c][g];
          u16 hh = f2bf(vv);
          Gt[row*XS_STR + col] = f2bf(vv - bf2f(hh));   // Glo
        }
    __syncthreads();                       // bar3: Glo visible

    // ---- logits B: Glo@Xhi^T (regs)
    #pragma unroll
    for (int kk=0;kk<8;kk++){
      const int ko = (kk<<5) + koq;
      short8 A = *(const short8*)&Gt[(rs+m16)*XS_STR + ko];
      __builtin_amdgcn_s_setprio(1);
      L[0] = MFMA16(A, XB[kk*2+0], L[0]);
      L[1] = MFMA16(A, XB[kk*2+1], L[1]);
      __builtin_amdgcn_s_setprio(0);
    }

    // ---- softmax: local (32-z half) max/sum, cross-wave merge via SMf
    float mxl[4], sml[4];
    #pragma unroll
    for (int g=0; g<4; g++){
      float mx = fmaxf(L[0][g], L[1][g]);
      #pragma unroll
      for (int off=1; off<16; off<<=1) mx = fmaxf(mx, __shfl_xor(mx, off, 64));
      float sum = 0.f;
      #pragma unroll
      for (int c=0;c<2;c++){ float e = __expf(L[c][g]-mx); L[c][g] = e; sum += e; }
      #pragma unroll
      for (int off=1; off<16; off<<=1) sum += __shfl_xor(sum, off, 64);
      mxl[g] = mx; sml[g] = sum;
      if (m16 == 0){
        int row = rs + quad*4 + g;
        SMf[row*4 + zh*2]     = mx;
        SMf[row*4 + zh*2 + 1] = sum;
      }
    }
    __syncthreads();                       // bar4: SMf visible
    #pragma unroll
    for (int g=0; g<4; g++){
      int row = rs + quad*4 + g;
      float mxo = SMf[row*4 + (zh^1)*2];
      float smo = SMf[row*4 + (zh^1)*2 + 1];
      float M   = fmaxf(mxl[g], mxo);
      float al  = __expf(mxl[g]-M), ao = __expf(mxo-M);
      float scale = al / (sml[g]*al + smo*ao);
      #pragma unroll
      for (int c=0;c<2;c++)
        Ps[row*PS_STR + (zh<<5) + c*16 + m16] = f2bf(L[c][g]*scale);
    }
    __syncthreads();                       // bar5: Ps visible

    // ---- Y = P @ Xv over wave's 32 cols; Z += so * Y
    #pragma unroll
    for (int r=0;r<4;r++){ acc[r][0] = zf; acc[r][1] = zf; }
    #pragma unroll
    for (int kk=0;kk<2;kk++){
      const int ko = (kk<<5) + koq;
      short8 A[4], Bf[2];
      #pragma unroll
      for (int r=0;r<4;r++) A[r]  = *(const short8*)&Ps[(r*16+m16)*PS_STR + ko];
      #pragma unroll
      for (int c=0;c<2;c++) Bf[c] = *(const short8*)&Xvt[(cw + c*16 + m16)*WT_STR + ko];
      #pragma unroll
      for (int r=0;r<4;r++)
        #pragma unroll
        for (int c=0;c<2;c++) acc[r][c] = MFMA16(A[r], Bf[c], acc[r][c]);
    }
    float sc[2];
    sc[0] = soP[gh*256 + cw + m16];
    sc[1] = soP[gh*256 + cw + 16 + m16];
    #pragma unroll
    for (int r=0;r<4;r++)
      #pragma unroll
      for (int c=0;c<2;c++)
        #pragma unroll
        for (int g=0; g<4; g++) Z[r][c][g] += sc[c]*acc[r][c][g];
    // no trailing barrier: next head's Gt writes precede bar1; all Gt/Ps/SMf
    // reads of head h complete before that head's bar4/bar5.
  }

  // ---- epilogue: atomic accumulate into pre-zeroed out
  #pragma unroll
  for (int r=0;r<4;r++)
    #pragma unroll
    for (int c=0;c<2;c++)
      #pragma unroll
      for (int g=0; g<4; g++){
        int t   = r*16 + quad*4 + g;
        int col = cw + c*16 + m16;
        atomicAdd(&out[tok(t) + col], Z[r][c][g]);
      }
}

extern "C" void kernel_launch(void* const* d_in, const int* in_sizes, int n_in,
                              void* d_out, int out_size, void* d_ws, size_t ws_size,
                              hipStream_t stream) {
  const float* x = (const float*)d_in[0];
  const float* q = (const float*)d_in[1];
  const float* k = (const float*)d_in[2];
  const float* v = (const float*)d_in[3];
  const float* o = (const float*)d_in[4];
  u16* ws   = (u16*)d_ws;                    // ~2.38 MB
  u16* mhi  = ws;
  u16* mlo  = ws + 524288;
  u16* vT   = ws + 1179648;
  float* soP = (float*)(ws + 1245184);
  float* out = (float*)d_out;

  (void)hipFuncSetAttribute(reinterpret_cast<const void*>(&prep_mh_kernel),
                            hipFuncAttributeMaxDynamicSharedMemorySize, MH_SMEM);
  prep_mh_kernel<<<1040, 256, MH_SMEM, stream>>>(q, k, v, o, mhi, mlo, vT, soP,
                                                 (float4*)d_out);

  (void)hipFuncSetAttribute(reinterpret_cast<const void*>(&attn_kernel),
                            hipFuncAttributeMaxDynamicSharedMemorySize, SMEM_BYTES);
  attn_kernel<<<1024, 512, SMEM_BYTES, stream>>>(x, mhi, mlo, vT, soP, out);
}

// Round 8
// 331.914 us; speedup vs baseline: 1.9656x; 1.0000x over previous
//
#include <hip/hip_runtime.h>

typedef unsigned short u16;
typedef __attribute__((ext_vector_type(8))) short short8;
typedef __attribute__((ext_vector_type(4))) float f32x4;

__device__ __forceinline__ float bf2f(u16 u){ return __uint_as_float(((unsigned)u)<<16); }
__device__ __forceinline__ u16 f2bf(float f){
  unsigned u = __float_as_uint(f);
  unsigned r = u + 0x7fffu + ((u>>16)&1u);   // RNE (no NaN/inf in this problem)
  return (u16)(r>>16);
}

#define MFMA16(a,b,c) __builtin_amdgcn_mfma_f32_16x16x32_bf16(a,b,c,0,0,0)

// ---- attn LDS layout (u16 offsets) - ROUND-0 VERBATIM (best known: attn
// ~266us steady, VGPR 128 no-spill, MfmaUtil ~23). Strides 264/72: row-stride
// ≡ 4 banks -> fragment reads serialize only to the wave64 minimum.
static constexpr int XS_STR  = 264;
static constexpr int PS_STR  = 72;
static constexpr int WT_STR  = 72;
static constexpr int XHI_OFF = 0;         // 64x264
static constexpr int XLO_OFF = 16896;
static constexpr int GT_OFF  = 33792;     // 64x264, Ghi then Glo per head
static constexpr int XVT_OFF = 50688;     // 256x72, persistent Xv^T
static constexpr int PS_OFF  = 69120;     // 64x72
static constexpr int SMRE_OFF= 73728;     // 64 rows x 2 halves x (mx,sum) f32
static constexpr int SMEM_BYTES = (73728 + 512)*2;   // 148480 B

// ---- prep_mh LDS: mh role Chi/Clo 64x40 (10240 B); vT role Ts 64x65 f32
// (16640 B) -> 16640 B total (was 44032: q-staging removed)
static constexpr int MH_SMEM = 16640;

// ---- ws layout (u16): mhi[524288] | mlo[524288] | (unused)
//                       | vT[65536] | soP[4096 u16 = 2048 f32]   (~2.38 MB)

// Fused prep+mh, ONE dispatch. Roles: blk<256 mh (q AND k A/B-fragments
// built directly from global f32 with inline hi/lo conversion - both are
// L1/L2-resident; no LDS staging, no barrier #1) | 256..271 vT |
// 272..527 so | 528..1039 zero out.
__global__ __launch_bounds__(256,1) void prep_mh_kernel(
    const float* __restrict__ q, const float* __restrict__ k,
    const float* __restrict__ v, const float* __restrict__ o,
    u16* __restrict__ mhi, u16* __restrict__ mlo, u16* __restrict__ vT,
    float* __restrict__ soP, float4* __restrict__ outz)
{
  extern __shared__ u16 sm[];
  const int blk = blockIdx.x, tid = threadIdx.x;

  if (blk < 256){
    // ---- mh role: MhT[h][dp][d] = sum_ko q[h][d][ko]*k[dp][ko], hi/lo bf16
    // 256 blocks (8h x 8 d-tiles(32) x 4 dp-tiles(64))
    u16* Chi = sm;               // 64x40  [dp-local][d-row-local]
    u16* Clo = sm + 2560;

    const int w = tid >> 6, lane = tid & 63;
    const int quad = lane >> 4, m16 = lane & 15;
    const int cw2 = w << 4, koq = quad << 3;
    const int h   = blk >> 5;
    const int rr  = blk & 31;
    const int dt  = (rr >> 2) << 5;          // d-tile (32 rows)
    const int dpq = (rr & 3) << 6;           // dp-tile (64 cols)

    // inline f32x8 -> bf16 hi/lo fragment builder
    auto conv8 = [&](const float* p, short8& hi, short8& lo){
      const float4 f0 = *(const float4*)p;
      const float4 f1 = *(const float4*)(p + 4);
      float fv[8] = {f0.x,f0.y,f0.z,f0.w,f1.x,f1.y,f1.z,f1.w};
      #pragma unroll
      for (int e=0;e<8;e++){
        u16 hh = f2bf(fv[e]);
        hi[e] = (short)hh;
        lo[e] = (short)f2bf(fv[e]-bf2f(hh));
      }
    };

    const float* qrow0 = q + (((h<<8)+dt+m16)<<8);      // A row m16
    const float* qrow1 = q + (((h<<8)+dt+16+m16)<<8);   // A row 16+m16
    const float* krow  = k + ((dpq+cw2+m16)<<8);        // B row (this lane)

    const f32x4 zf = {0.f,0.f,0.f,0.f};
    f32x4 a0 = zf, a1 = zf;
    #pragma unroll
    for (int kk=0;kk<8;kk++){
      const int ko = (kk<<5) + koq;
      short8 Ah0, Al0, Ah1, Al1, Bh, Bl;
      conv8(qrow0 + ko, Ah0, Al0);
      conv8(qrow1 + ko, Ah1, Al1);
      conv8(krow  + ko, Bh,  Bl);
      a0 = MFMA16(Ah0,Bh,a0); a0 = MFMA16(Ah0,Bl,a0); a0 = MFMA16(Al0,Bh,a0);
      a1 = MFMA16(Ah1,Bh,a1); a1 = MFMA16(Ah1,Bl,a1); a1 = MFMA16(Al1,Bh,a1);
    }

    const int dpl = cw2 + m16;
    #pragma unroll
    for (int g=0; g<4; g++){
      float v0 = a0[g]; u16 h0 = f2bf(v0);
      Chi[dpl*40 + quad*4+g] = h0;
      Clo[dpl*40 + quad*4+g] = f2bf(v0 - bf2f(h0));
      float v1 = a1[g]; u16 h1 = f2bf(v1);
      Chi[dpl*40 + 16 + quad*4+g] = h1;
      Clo[dpl*40 + 16 + quad*4+g] = f2bf(v1 - bf2f(h1));
    }
    __syncthreads();

    int dpo = tid >> 2, i8 = (tid & 3) << 3;
    *(int4*)&mhi[(((h<<8)+dpq+dpo)<<8) + dt + i8] = *(const int4*)&Chi[dpo*40 + i8];
    *(int4*)&mlo[(((h<<8)+dpq+dpo)<<8) + dt + i8] = *(const int4*)&Clo[dpo*40 + i8];

  } else if (blk < 272){
    // ---- vT role (16 blocks)
    float* Ts = (float*)sm;                // 64x65
    int t = blk - 256;
    const int bi = (t>>2)<<6, bj = (t&3)<<6;
    #pragma unroll
    for (int p=0;p<4;p++){
      int idx4 = tid + (p<<8);
      int i = idx4 >> 4, c4 = (idx4 & 15) << 2;
      const float4 f4 = *(const float4*)(v + ((bi+i)<<8) + bj + c4);
      Ts[i*65+c4]=f4.x; Ts[i*65+c4+1]=f4.y; Ts[i*65+c4+2]=f4.z; Ts[i*65+c4+3]=f4.w;
    }
    __syncthreads();
    #pragma unroll
    for (int p=0;p<2;p++){
      int ch = tid + (p<<8);
      int j = ch >> 3, i8 = (ch & 7) << 3;
      short8 t8;
      #pragma unroll
      for (int e=0;e<8;e++) t8[e] = (short)f2bf(Ts[(i8+e)*65 + j]);
      *(short8*)&vT[((bj+j)<<8) + bi + i8] = t8;
    }
  } else if (blk < 528){
    // ---- so role (256 blocks: 8 h x 32 chunks of 8 rows)
    int p = blk - 272;
    int h = p >> 5, base = (p & 31) << 3;
    int w = tid >> 6, l = tid & 63;
    #pragma unroll
    for (int i=0;i<2;i++){
      int row = base + w*2 + i;
      const float4 f4 = *(const float4*)(o + (((h<<8)+row)<<8) + (l<<2));
      float s = f4.x + f4.y + f4.z + f4.w;
      #pragma unroll
      for (int off=32; off>=1; off>>=1) s += __shfl_xor(s, off, 64);
      if (l==0) soP[(h<<8)+row] = s;
    }
  } else {
    // ---- zero-out role (512 blocks x 4096 float4)
    int z = blk - 528;
    const float4 zf4 = {0.f,0.f,0.f,0.f};
    #pragma unroll
    for (int i=0;i<16;i++) outz[z*4096 + i*256 + tid] = zf4;
  }
}

// Merged attention - FROZEN r7 build (best measured: 266.1-266.6us steady).
// Latency-bound at 2 waves/SIMD; both structural escapes measured closed:
// 16 waves/CU needs total VGPR+AGPR<=128/wave (thin-wave r4/r5 lost 2x);
// barrier-count restructures lose more in LDS re-reads than they save
// (r2/r3). Do NOT touch: regalloc sits exactly at the 128-VGPR boundary.
__global__ __launch_bounds__(512,2) void attn_kernel(
    const float* __restrict__ x, const u16* __restrict__ mhiP,
    const u16* __restrict__ mloP, const u16* __restrict__ vT,
    const float* __restrict__ soP, float* __restrict__ out)
{
  extern __shared__ u16 sm[];
  u16* Xhi = sm + XHI_OFF;
  u16* Xlo = sm + XLO_OFF;
  u16* Gt  = sm + GT_OFF;
  u16* Xvt = sm + XVT_OFF;
  u16* Ps  = sm + PS_OFF;
  float* SMf = (float*)(sm + SMRE_OFF);   // [row][half][mx,sum]

  const int tid  = threadIdx.x;
  const int w    = tid >> 6, lane = tid & 63;
  const int quad = lane >> 4, m16 = lane & 15;
  const int br   = blockIdx.x >> 9;
  const int idx  = blockIdx.x & 511;
  const int b    = idx >> 6, s = idx & 63;
  const int cw   = w << 5;            // 32-col strip for mm3/Xv/Y
  const int rs   = (w >> 1) << 4;     // logits: 16-row strip
  const int zh   = w & 1;             // logits: z half (32 cols)
  const int koq  = quad << 3;

  auto tok = [&](int t)->int {
    int m = br ? s : t;
    int n = br ? t : s;
    return (((b<<6) + m) << 14) + (n << 8);
  };

  // ---- stage X hi/lo (4096 float4, 8 iters x 512 threads)
  #pragma unroll
  for (int i=0;i<8;i++){
    int idx4 = i*512 + tid;
    int tr = idx4 >> 6, c4 = (idx4 & 63) << 2;
    const float4 xv = *(const float4*)(x + tok(tr) + c4);
    ushort4 hv, lv;
    hv.x=f2bf(xv.x); lv.x=f2bf(xv.x-bf2f(hv.x));
    hv.y=f2bf(xv.y); lv.y=f2bf(xv.y-bf2f(hv.y));
    hv.z=f2bf(xv.z); lv.z=f2bf(xv.z-bf2f(hv.z));
    hv.w=f2bf(xv.w); lv.w=f2bf(xv.w-bf2f(hv.w));
    *(ushort4*)&Xhi[tr*XS_STR + c4] = hv;
    *(ushort4*)&Xlo[tr*XS_STR + c4] = lv;
  }
  __syncthreads();

  // ---- persist logits B-side Xhi fragments (constant across heads): 64 VGPRs
  short8 XB[16];
  #pragma unroll
  for (int kk=0;kk<8;kk++)
    #pragma unroll
    for (int c=0;c<2;c++)
      XB[kk*2+c] = *(const short8*)&Xhi[((zh<<5) + c*16 + m16)*XS_STR + (kk<<5) + koq];

  const f32x4 zf = {0.f,0.f,0.f,0.f};
  f32x4 acc[4][2];

  // acc = Xhi@Whi + Xhi@Wlo + Xlo@Whi over wave's 32-col strip, dbuf B-loads
  auto mm3 = [&](const u16* __restrict__ Whi, const u16* __restrict__ Wlo){
    #pragma unroll
    for (int r=0;r<4;r++){ acc[r][0] = zf; acc[r][1] = zf; }
    short8 Bh[2][2], Bl[2][2];
    #pragma unroll
    for (int c=0;c<2;c++){
      Bh[0][c] = *(const short8*)&Whi[(cw + c*16 + m16)*256 + koq];
      Bl[0][c] = *(const short8*)&Wlo[(cw + c*16 + m16)*256 + koq];
    }
    #pragma unroll
    for (int kk=0;kk<8;kk++){
      const int cur = kk&1, nxt = cur^1;
      if (kk<7){
        const int ko2 = ((kk+1)<<5) + koq;
        #pragma unroll
        for (int c=0;c<2;c++){
          Bh[nxt][c] = *(const short8*)&Whi[(cw + c*16 + m16)*256 + ko2];
          Bl[nxt][c] = *(const short8*)&Wlo[(cw + c*16 + m16)*256 + ko2];
        }
      }
      const int ko = (kk<<5) + koq;
      short8 Ah[4], Al[4];
      #pragma unroll
      for (int r=0;r<4;r++) Ah[r] = *(const short8*)&Xhi[(r*16+m16)*XS_STR + ko];
      #pragma unroll
      for (int r=0;r<4;r++) Al[r] = *(const short8*)&Xlo[(r*16+m16)*XS_STR + ko];
      __builtin_amdgcn_s_setprio(1);
      #pragma unroll
      for (int r=0;r<4;r++)
        #pragma unroll
        for (int c=0;c<2;c++){
          acc[r][c] = MFMA16(Ah[r], Bh[cur][c], acc[r][c]);
          acc[r][c] = MFMA16(Ah[r], Bl[cur][c], acc[r][c]);
          acc[r][c] = MFMA16(Al[r], Bh[cur][c], acc[r][c]);
        }
      __builtin_amdgcn_s_setprio(0);
    }
  };

  // ---- Xv = Xhi @ vT over wave's 32 cols; store Xv^T (unscaled) in LDS
  {
    #pragma unroll
    for (int r=0;r<4;r++){ acc[r][0] = zf; acc[r][1] = zf; }
    #pragma unroll
    for (int kk=0;kk<8;kk++){
      const int ko = (kk<<5) + koq;
      short8 A[4], Bf[2];
      #pragma unroll
      for (int r=0;r<4;r++) A[r]  = *(const short8*)&Xhi[(r*16+m16)*XS_STR + ko];
      #pragma unroll
      for (int c=0;c<2;c++) Bf[c] = *(const short8*)&vT[(cw + c*16 + m16)*256 + ko];
      #pragma unroll
      for (int r=0;r<4;r++)
        #pragma unroll
        for (int c=0;c<2;c++) acc[r][c] = MFMA16(A[r], Bf[c], acc[r][c]);
    }
    #pragma unroll
    for (int r=0;r<4;r++)
      #pragma unroll
      for (int c=0;c<2;c++)
        #pragma unroll
        for (int g=0; g<4; g++){
          int z  = r*16 + quad*4 + g;
          int vc = cw + c*16 + m16;
          Xvt[vc*WT_STR + z] = f2bf(acc[r][c][g]);
        }
    // visible after bar1 of head 0
  }

  f32x4 Z[4][2];
  #pragma unroll
  for (int r=0;r<4;r++){ Z[r][0] = zf; Z[r][1] = zf; }

  for (int h=0; h<4; h++){
    const int gh = br*4 + h;

    // ---- G = X @ Mh[gh] (3-term hi/lo); write Ghi (all rows x own 32 cols)
    mm3(mhiP + gh*65536, mloP + gh*65536);
    #pragma unroll
    for (int r=0;r<4;r++)
      #pragma unroll
      for (int c=0;c<2;c++)
        #pragma unroll
        for (int g=0; g<4; g++){
          int row = r*16 + quad*4 + g;
          int col = cw + c*16 + m16;
          Gt[row*XS_STR + col] = f2bf(acc[r][c][g]);
        }
    __syncthreads();                       // bar1: Ghi (+Xvt at h==0) visible

    // ---- logits A: Ghi@Xhi^T (regs) + Ghi@Xlo^T. Rows rs..rs+16, z half zh.
    f32x4 L[2];
    L[0] = zf; L[1] = zf;
    #pragma unroll
    for (int kk=0;kk<8;kk++){
      const int ko = (kk<<5) + koq;
      short8 A = *(const short8*)&Gt[(rs+m16)*XS_STR + ko];
      short8 Bl0 = *(const short8*)&Xlo[((zh<<5) + m16)*XS_STR + ko];
      short8 Bl1 = *(const short8*)&Xlo[((zh<<5) + 16 + m16)*XS_STR + ko];
      __builtin_amdgcn_s_setprio(1);
      L[0] = MFMA16(A, XB[kk*2+0], L[0]);
      L[0] = MFMA16(A, Bl0, L[0]);
      L[1] = MFMA16(A, XB[kk*2+1], L[1]);
      L[1] = MFMA16(A, Bl1, L[1]);
      __builtin_amdgcn_s_setprio(0);
    }
    __syncthreads();                       // bar2: Gt-hi reads done -> overwrite
    #pragma unroll
    for (int r=0;r<4;r++)
      #pragma unroll
      for (int c=0;c<2;c++)
        #pragma unroll
        for (int g=0; g<4; g++){
          int row = r*16 + quad*4 + g;
          int col = cw + c*16 + m16;
          float vv = acc[r][c][g];
          u16 hh = f2bf(vv);
          Gt[row*XS_STR + col] = f2bf(vv - bf2f(hh));   // Glo
        }
    __syncthreads();                       // bar3: Glo visible

    // ---- logits B: Glo@Xhi^T (regs)
    #pragma unroll
    for (int kk=0;kk<8;kk++){
      const int ko = (kk<<5) + koq;
      short8 A = *(const short8*)&Gt[(rs+m16)*XS_STR + ko];
      __builtin_amdgcn_s_setprio(1);
      L[0] = MFMA16(A, XB[kk*2+0], L[0]);
      L[1] = MFMA16(A, XB[kk*2+1], L[1]);
      __builtin_amdgcn_s_setprio(0);
    }

    // ---- softmax: local (32-z half) max/sum, cross-wave merge via SMf
    float mxl[4], sml[4];
    #pragma unroll
    for (int g=0; g<4; g++){
      float mx = fmaxf(L[0][g], L[1][g]);
      #pragma unroll
      for (int off=1; off<16; off<<=1) mx = fmaxf(mx, __shfl_xor(mx, off, 64));
      float sum = 0.f;
      #pragma unroll
      for (int c=0;c<2;c++){ float e = __expf(L[c][g]-mx); L[c][g] = e; sum += e; }
      #pragma unroll
      for (int off=1; off<16; off<<=1) sum += __shfl_xor(sum, off, 64);
      mxl[g] = mx; sml[g] = sum;
      if (m16 == 0){
        int row = rs + quad*4 + g;
        SMf[row*4 + zh*2]     = mx;
        SMf[row*4 + zh*2 + 1] = sum;
      }
    }
    __syncthreads();                       // bar4: SMf visible
    #pragma unroll
    for (int g=0; g<4; g++){
      int row = rs + quad*4 + g;
      float mxo = SMf[row*4 + (zh^1)*2];
      float smo = SMf[row*4 + (zh^1)*2 + 1];
      float M   = fmaxf(mxl[g], mxo);
      float al  = __expf(mxl[g]-M), ao = __expf(mxo-M);
      float scale = al / (sml[g]*al + smo*ao);
      #pragma unroll
      for (int c=0;c<2;c++)
        Ps[row*PS_STR + (zh<<5) + c*16 + m16] = f2bf(L[c][g]*scale);
    }
    __syncthreads();                       // bar5: Ps visible

    // ---- Y = P @ Xv over wave's 32 cols; Z += so * Y
    #pragma unroll
    for (int r=0;r<4;r++){ acc[r][0] = zf; acc[r][1] = zf; }
    #pragma unroll
    for (int kk=0;kk<2;kk++){
      const int ko = (kk<<5) + koq;
      short8 A[4], Bf[2];
      #pragma unroll
      for (int r=0;r<4;r++) A[r]  = *(const short8*)&Ps[(r*16+m16)*PS_STR + ko];
      #pragma unroll
      for (int c=0;c<2;c++) Bf[c] = *(const short8*)&Xvt[(cw + c*16 + m16)*WT_STR + ko];
      #pragma unroll
      for (int r=0;r<4;r++)
        #pragma unroll
        for (int c=0;c<2;c++) acc[r][c] = MFMA16(A[r], Bf[c], acc[r][c]);
    }
    float sc[2];
    sc[0] = soP[gh*256 + cw + m16];
    sc[1] = soP[gh*256 + cw + 16 + m16];
    #pragma unroll
    for (int r=0;r<4;r++)
      #pragma unroll
      for (int c=0;c<2;c++)
        #pragma unroll
        for (int g=0; g<4; g++) Z[r][c][g] += sc[c]*acc[r][c][g];
    // no trailing barrier: next head's Gt writes precede bar1; all Gt/Ps/SMf
    // reads of head h complete before that head's bar4/bar5.
  }

  // ---- epilogue: atomic accumulate into pre-zeroed out
  #pragma unroll
  for (int r=0;r<4;r++)
    #pragma unroll
    for (int c=0;c<2;c++)
      #pragma unroll
      for (int g=0; g<4; g++){
        int t   = r*16 + quad*4 + g;
        int col = cw + c*16 + m16;
        atomicAdd(&out[tok(t) + col], Z[r][c][g]);
      }
}

extern "C" void kernel_launch(void* const* d_in, const int* in_sizes, int n_in,
                              void* d_out, int out_size, void* d_ws, size_t ws_size,
                              hipStream_t stream) {
  const float* x = (const float*)d_in[0];
  const float* q = (const float*)d_in[1];
  const float* k = (const float*)d_in[2];
  const float* v = (const float*)d_in[3];
  const float* o = (const float*)d_in[4];
  u16* ws   = (u16*)d_ws;                    // ~2.38 MB
  u16* mhi  = ws;
  u16* mlo  = ws + 524288;
  u16* vT   = ws + 1179648;
  float* soP = (float*)(ws + 1245184);
  float* out = (float*)d_out;

  (void)hipFuncSetAttribute(reinterpret_cast<const void*>(&prep_mh_kernel),
                            hipFuncAttributeMaxDynamicSharedMemorySize, MH_SMEM);
  prep_mh_kernel<<<1040, 256, MH_SMEM, stream>>>(q, k, v, o, mhi, mlo, vT, soP,
                                                 (float4*)d_out);

  (void)hipFuncSetAttribute(reinterpret_cast<const void*>(&attn_kernel),
                            hipFuncAttributeMaxDynamicSharedMemorySize, SMEM_BYTES);
  attn_kernel<<<1024, 512, SMEM_BYTES, stream>>>(x, mhi, mlo, vT, soP, out);
}